// Round 8
// baseline (220.683 us; speedup 1.0000x reference)
//
#include <hip/hip_runtime.h>

namespace {
constexpr int kL0 = 16384;
constexpr int kN1 = 8195;
constexpr int kN2 = 4101;

constexpr float RLc[8] = {
     0.23037781330885523f,  0.7148465705525415f,   0.6308807679295904f,
    -0.02798376941698385f, -0.18703481171888114f,  0.030841381835986965f,
     0.032883011666982945f, -0.010597401785069032f };

// Composite 3-level low-reconstruction bank: low[8q+r] = sum_m W[r][m]*a3[q+m]
// (verified R5-R7)
struct WT { float w[8][7]; };
constexpr WT make_w() {
    WT W{};
    for (int r = 0; r < 8; ++r) {
        const int r2 = r >> 1, pi = r & 1;
        for (int u = 0; u < 4; ++u) {
            const float cu = RLc[6 + pi - 2 * u];
            const int k = r2 + u, k2 = k >> 1, pk = k & 1;
            for (int s = 0; s < 4; ++s) {
                const float cs = RLc[6 + pk - 2 * s];
                const int j = k2 + s, j2 = j >> 1, pj = j & 1;
                for (int t = 0; t < 4; ++t)
                    W.w[r][j2 + t] += cu * cs * RLc[6 + pj - 2 * t];
            }
        }
    }
    return W;
}

// Composite 3-level analysis low-pass: a3[n] = sum_j H3[j] * x[8n-42+j]
// from a1[n]=sum RL[k]x[2n-6+k] applied three times: j = 4k2+2k1+k0.
struct H3T { float v[50]; };
constexpr H3T make_h3() {
    H3T h{};
    for (int a = 0; a < 8; ++a)
        for (int b = 0; b < 8; ++b)
            for (int c = 0; c < 8; ++c)
                h.v[4 * a + 2 * b + c] += RLc[a] * RLc[b] * RLc[c];
    return h;
}

__device__ constexpr float RL[8] = {
     0.23037781330885523f,  0.7148465705525415f,   0.6308807679295904f,
    -0.02798376941698385f, -0.18703481171888114f,  0.030841381835986965f,
     0.032883011666982945f, -0.010597401785069032f };
__device__ constexpr WT W = make_w();
__device__ constexpr H3T H3 = make_h3();
} // namespace

__device__ __forceinline__ int reflect(int g, int N) {
    if (g < 0)  g = -1 - g;
    if (g >= N) g = 2 * N - 1 - g;
    return g;
}

// Block = 1 wave (64 threads). Thread t (= quarter*64+lane) owns outputs
// [64t, 64t+63] of one row: a3[q0..q0+13] (q0=8t) -> 64 low/high values.
__global__ void __launch_bounds__(64, 6)
wavelet_stream(const float* __restrict__ x, float* __restrict__ out, int rows) {
    const int lane    = threadIdx.x;
    const int b       = blockIdx.x;
    const int row     = b >> 2;
    const int quarter = b & 3;
    const int t       = (quarter << 6) | lane;   // 0..255
    const int q0      = t << 3;
    const float* __restrict__ xr = x + (size_t)row * kL0;

    // ---- boundary a3 precompute (static index sets; edge quarters only) ----
    // slow a3: n in [0,5] u [2048,2053]; deps: a2 [0,11]u[4090,4100],
    // a1 [0,23]u[8174,8194], x [0,53]u[16342,16383] (reflection-closed).
    __shared__ float sa1b[45], sa2b[23], sa3b[12];
    if (quarter == 0 || quarter == 3) {
        if (lane < 45) {
            const int i = (lane < 24) ? lane : 8174 + (lane - 24);
            float s = 0.f;
            #pragma unroll
            for (int k = 0; k < 8; ++k)
                s = fmaf(xr[reflect(2 * i - 6 + k, kL0)], RL[k], s);
            sa1b[lane] = s;
        }
        __syncthreads();
        if (lane < 23) {
            const int j = (lane < 12) ? lane : 4090 + (lane - 12);
            float s = 0.f;
            #pragma unroll
            for (int k = 0; k < 8; ++k) {
                const int i  = reflect(2 * j - 6 + k, kN1);
                const int sl = (i <= 23) ? i : 24 + (i - 8174);
                s = fmaf(sa1b[sl], RL[k], s);
            }
            sa2b[lane] = s;
        }
        __syncthreads();
        if (lane < 12) {
            const int n = (lane < 6) ? lane : 2048 + (lane - 6);
            float s = 0.f;
            #pragma unroll
            for (int k = 0; k < 8; ++k) {
                const int j  = reflect(2 * n - 6 + k, kN2);
                const int sl = (j <= 11) ? j : 12 + (j - 4090);
                s = fmaf(sa2b[sl], RL[k], s);
            }
            sa3b[lane] = s;
        }
        __syncthreads();
    }

    // ---- a3[q0 .. q0+13] ----
    float acc[14];
    if (t >= 1 && t <= 254) {
        // fast: one 160-float window x[8q0-48 .. 8q0+111]; tap of a3[q0+m]
        // at window pos e = 8m+6+j, j in [0,49]. All taps static after unroll.
        #pragma unroll
        for (int m = 0; m < 14; ++m) acc[m] = 0.f;
        const float4* __restrict__ xw4 =
            reinterpret_cast<const float4*>(xr + (8 * q0 - 48));
        #pragma unroll
        for (int c = 0; c < 40; ++c) {
            const float4 v = xw4[c];
            #pragma unroll
            for (int k = 0; k < 4; ++k) {
                const int e = 4 * c + k;
                const float vk = (k == 0) ? v.x : (k == 1) ? v.y : (k == 2) ? v.z : v.w;
                const int mlo = (e >= 55) ? ((e - 48) >> 3) : 0;   // ceil((e-55)/8)
                int mhi = (e >= 6) ? ((e - 6) >> 3) : -1;
                if (mhi > 13) mhi = 13;
                #pragma unroll
                for (int m = mlo; m <= mhi; ++m)
                    acc[m] = fmaf(vk, H3.v[e - 8 * m - 6], acc[m]);
            }
        }
    } else {
        // slow (t==0 / t==255): interior coeffs by direct 50-tap, edge coeffs
        // from the precomputed LDS table.
        #pragma unroll
        for (int m = 0; m < 14; ++m) {
            const int n = q0 + m;
            if (n >= 6 && n <= 2047) {
                const float* p = xr + (8 * n - 42);
                float s = 0.f;
                #pragma unroll
                for (int j = 0; j < 50; ++j) s = fmaf(p[j], H3.v[j], s);
                acc[m] = s;
            } else {
                acc[m] = sa3b[(n <= 5) ? n : 6 + (n - 2048)];
            }
        }
    }

    // ---- outputs: low = W * a3; high = x - low ----
    float* __restrict__ lowp  = out + (size_t)row * kL0;
    float* __restrict__ highp = out + (size_t)rows * kL0 + (size_t)row * kL0;
    #pragma unroll
    for (int g = 0; g < 8; ++g) {
        float lo[8];
        #pragma unroll
        for (int r = 0; r < 8; ++r) {
            float s = acc[g] * W.w[r][0];
            #pragma unroll
            for (int m = 1; m < 7; ++m) s = fmaf(acc[g + m], W.w[r][m], s);
            lo[r] = s;
        }
        const int o = (q0 + g) << 3;
        const float4 xv0 = *reinterpret_cast<const float4*>(xr + o);
        const float4 xv1 = *reinterpret_cast<const float4*>(xr + o + 4);
        *reinterpret_cast<float4*>(lowp + o)      = make_float4(lo[0], lo[1], lo[2], lo[3]);
        *reinterpret_cast<float4*>(lowp + o + 4)  = make_float4(lo[4], lo[5], lo[6], lo[7]);
        *reinterpret_cast<float4*>(highp + o)     = make_float4(xv0.x - lo[0], xv0.y - lo[1],
                                                                xv0.z - lo[2], xv0.w - lo[3]);
        *reinterpret_cast<float4*>(highp + o + 4) = make_float4(xv1.x - lo[4], xv1.y - lo[5],
                                                                xv1.z - lo[6], xv1.w - lo[7]);
    }
}

extern "C" void kernel_launch(void* const* d_in, const int* in_sizes, int n_in,
                              void* d_out, int out_size, void* d_ws, size_t ws_size,
                              hipStream_t stream) {
    (void)n_in; (void)d_ws; (void)ws_size; (void)out_size;
    const float* x = (const float*)d_in[0];
    float* out = (float*)d_out;
    const int rows = in_sizes[0] / kL0;           // 2048
    const int blocks = rows * 4;                  // 8192 one-wave blocks
    hipLaunchKernelGGL(wavelet_stream, dim3(blocks), dim3(64), 0, stream,
                       x, out, rows);
}

// Round 9
// 118.309 us; speedup vs baseline: 1.8653x; 1.8653x over previous
//
#include <hip/hip_runtime.h>

namespace {
constexpr int kL0 = 16384;
constexpr int kN1 = 8195;
constexpr int kN2 = 4101;
constexpr int kThreads = 256;

constexpr float RLc[8] = {
     0.23037781330885523f,  0.7148465705525415f,   0.6308807679295904f,
    -0.02798376941698385f, -0.18703481171888114f,  0.030841381835986965f,
     0.032883011666982945f, -0.010597401785069032f };

// Composite 3-level low-reconstruction bank: low[8q+r] = sum_m W[r][m]*a3[q+m]
// (verified R5-R8)
struct WT { float w[8][7]; };
constexpr WT make_w() {
    WT W{};
    for (int r = 0; r < 8; ++r) {
        const int r2 = r >> 1, pi = r & 1;
        for (int u = 0; u < 4; ++u) {
            const float cu = RLc[6 + pi - 2 * u];
            const int k = r2 + u, k2 = k >> 1, pk = k & 1;
            for (int s = 0; s < 4; ++s) {
                const float cs = RLc[6 + pk - 2 * s];
                const int j = k2 + s, j2 = j >> 1, pj = j & 1;
                for (int t = 0; t < 4; ++t)
                    W.w[r][j2 + t] += cu * cs * RLc[6 + pj - 2 * t];
            }
        }
    }
    return W;
}

// Composite 3-level analysis low-pass, padded to a float4-aligned window:
// a3[n] = sum_{j=0..49} H3[j]*x[8n-42+j] = sum_{e=0..51} H3p[e]*x[8n-44+e]
// (H3 verified R8; H3p[0]=H3p[1]=0)
struct H3PT { float v[52]; };
constexpr H3PT make_h3p() {
    H3PT h{};
    for (int a = 0; a < 8; ++a)
        for (int b = 0; b < 8; ++b)
            for (int c = 0; c < 8; ++c)
                h.v[2 + 4 * a + 2 * b + c] += RLc[a] * RLc[b] * RLc[c];
    return h;
}

__device__ constexpr float RL[8] = {
     0.23037781330885523f,  0.7148465705525415f,   0.6308807679295904f,
    -0.02798376941698385f, -0.18703481171888114f,  0.030841381835986965f,
     0.032883011666982945f, -0.010597401785069032f };
__device__ constexpr WT W = make_w();
__device__ constexpr H3PT H3P = make_h3p();
} // namespace

__device__ __forceinline__ int reflect(int g, int N) {
    if (g < 0)  g = -1 - g;
    if (g >= N) g = 2 * N - 1 - g;
    return g;
}

// direct a3 for interior n in [6, 2047]: reads x[8n-44 .. 8n+7] (in-bounds)
__device__ __forceinline__ float a3_direct(const float* __restrict__ xr, int n) {
    const float4* __restrict__ p = reinterpret_cast<const float4*>(xr + (8 * n - 44));
    float s0 = 0.f, s1 = 0.f;
    #pragma unroll
    for (int c = 0; c < 13; ++c) {
        const float4 v = p[c];
        s0 = fmaf(v.x, H3P.v[4 * c + 0], s0);
        s1 = fmaf(v.y, H3P.v[4 * c + 1], s1);
        s0 = fmaf(v.z, H3P.v[4 * c + 2], s0);
        s1 = fmaf(v.w, H3P.v[4 * c + 3], s1);
    }
    return s0 + s1;
}

__global__ void __launch_bounds__(kThreads, 6)
wavelet_hybrid(const float* __restrict__ x, float* __restrict__ out, int rows) {
    __shared__ float sa3[263];
    __shared__ float sa1b[45], sa2b[23], sa3b[12];

    const int tid  = threadIdx.x;
    const int row  = blockIdx.x >> 3;
    const int tile = blockIdx.x & 7;
    const int O    = tile << 11;
    const int q0   = tile << 8;
    const float* __restrict__ xr = x + (size_t)row * kL0;
    const bool edge = (tile == 0) || (tile == 7);

    // ---- boundary a3 table (R8-verified 3-step reflection recursion) ----
    if (edge) {
        if (tid < 45) {
            const int i = (tid < 24) ? tid : 8174 + (tid - 24);
            float s = 0.f;
            #pragma unroll
            for (int k = 0; k < 8; ++k)
                s = fmaf(xr[reflect(2 * i - 6 + k, kL0)], RL[k], s);
            sa1b[tid] = s;
        }
        __syncthreads();
        if (tid < 23) {
            const int j = (tid < 12) ? tid : 4090 + (tid - 12);
            float s = 0.f;
            #pragma unroll
            for (int k = 0; k < 8; ++k) {
                const int i  = reflect(2 * j - 6 + k, kN1);
                const int sl = (i <= 23) ? i : 24 + (i - 8174);
                s = fmaf(sa1b[sl], RL[k], s);
            }
            sa2b[tid] = s;
        }
        __syncthreads();
        if (tid < 12) {
            const int n = (tid < 6) ? tid : 2048 + (tid - 6);
            float s = 0.f;
            #pragma unroll
            for (int k = 0; k < 8; ++k) {
                const int j  = reflect(2 * n - 6 + k, kN2);
                const int sl = (j <= 11) ? j : 12 + (j - 4090);
                s = fmaf(sa2b[sl], RL[k], s);
            }
            sa3b[tid] = s;
        }
        __syncthreads();
    }

    // ---- a3 tile: sa3[t] = a3[q0+t], t in [0,262) ----
    {
        const int n = q0 + tid;
        sa3[tid] = (n >= 6 && n <= 2047)
                       ? a3_direct(xr, n)
                       : sa3b[(n <= 5) ? n : 6 + (n - 2048)];
        if (tid < 6) {
            const int nh = q0 + 256 + tid;
            sa3[256 + tid] = (nh <= 2047) ? a3_direct(xr, nh)
                                          : sa3b[6 + (nh - 2048)];
        }
    }
    __syncthreads();

    // ---- final: low[8q+r] via W bank; high = x - low (R5-verified layout) ----
    {
        const float4* xr4 = reinterpret_cast<const float4*>(xr + O + 8 * tid);
        const float4 xv0 = xr4[0], xv1 = xr4[1];
        float a[7];
        #pragma unroll
        for (int m = 0; m < 7; ++m) a[m] = sa3[tid + m];
        float lo[8];
        #pragma unroll
        for (int r = 0; r < 8; ++r) {
            float s = a[0] * W.w[r][0];
            #pragma unroll
            for (int m = 1; m < 7; ++m) s = fmaf(a[m], W.w[r][m], s);
            lo[r] = s;
        }
        float* __restrict__ lowp  = out + (size_t)row * kL0 + O + 8 * tid;
        float* __restrict__ highp = lowp + (size_t)rows * kL0;
        reinterpret_cast<float4*>(lowp)[0]  = make_float4(lo[0], lo[1], lo[2], lo[3]);
        reinterpret_cast<float4*>(lowp)[1]  = make_float4(lo[4], lo[5], lo[6], lo[7]);
        reinterpret_cast<float4*>(highp)[0] = make_float4(xv0.x - lo[0], xv0.y - lo[1],
                                                          xv0.z - lo[2], xv0.w - lo[3]);
        reinterpret_cast<float4*>(highp)[1] = make_float4(xv1.x - lo[4], xv1.y - lo[5],
                                                          xv1.z - lo[6], xv1.w - lo[7]);
    }
}

extern "C" void kernel_launch(void* const* d_in, const int* in_sizes, int n_in,
                              void* d_out, int out_size, void* d_ws, size_t ws_size,
                              hipStream_t stream) {
    (void)n_in; (void)d_ws; (void)ws_size; (void)out_size;
    const float* x = (const float*)d_in[0];
    float* out = (float*)d_out;
    const int rows = in_sizes[0] / kL0;           // 2048
    const int blocks = rows * 8;                  // 16384
    hipLaunchKernelGGL(wavelet_hybrid, dim3(blocks), dim3(kThreads), 0, stream,
                       x, out, rows);
}

// Round 10
// 116.489 us; speedup vs baseline: 1.8945x; 1.0156x over previous
//
#include <hip/hip_runtime.h>

namespace {
constexpr int kL0 = 16384;
constexpr int kN1 = 8195;
constexpr int kN2 = 4101;
constexpr int kThreads = 256;

constexpr int SXF = 2144;   // sx[t] <-> x[XB+t], XB = O-44; valid t in [2,2140)
constexpr int SA1 = 1066;
constexpr int SA2 = 530;
constexpr int SA3 = 262;

constexpr float RLc[8] = {
     0.23037781330885523f,  0.7148465705525415f,   0.6308807679295904f,
    -0.02798376941698385f, -0.18703481171888114f,  0.030841381835986965f,
     0.032883011666982945f, -0.010597401785069032f };

// Composite 3-level low-reconstruction bank (verified R5-R9):
// low[8q+r] = sum_m W[r][m]*a3[q+m]
struct WT { float w[8][7]; };
constexpr WT make_w() {
    WT W{};
    for (int r = 0; r < 8; ++r) {
        const int r2 = r >> 1, pi = r & 1;
        for (int u = 0; u < 4; ++u) {
            const float cu = RLc[6 + pi - 2 * u];
            const int k = r2 + u, k2 = k >> 1, pk = k & 1;
            for (int s = 0; s < 4; ++s) {
                const float cs = RLc[6 + pk - 2 * s];
                const int j = k2 + s, j2 = j >> 1, pj = j & 1;
                for (int t = 0; t < 4; ++t)
                    W.w[r][j2 + t] += cu * cs * RLc[6 + pj - 2 * t];
            }
        }
    }
    return W;
}

__device__ constexpr float RL[8] = {
     0.23037781330885523f,  0.7148465705525415f,   0.6308807679295904f,
    -0.02798376941698385f, -0.18703481171888114f,  0.030841381835986965f,
     0.032883011666982945f, -0.010597401785069032f };
__device__ constexpr WT W = make_w();
} // namespace

__device__ __forceinline__ int reflect(int g, int N) {
    if (g < 0)  g = -1 - g;
    if (g >= N) g = 2 * N - 1 - g;
    return g;
}

// 8-tap correlation; p at EVEN float index (8B-aligned), float2 reads
__device__ __forceinline__ float tap8f2(const float* __restrict__ p) {
    const float2* q = reinterpret_cast<const float2*>(p);
    const float2 q0 = q[0], q1 = q[1], q2 = q[2], q3 = q[3];
    float s = q0.x * RL[0];
    s = fmaf(q0.y, RL[1], s); s = fmaf(q1.x, RL[2], s); s = fmaf(q1.y, RL[3], s);
    s = fmaf(q2.x, RL[4], s); s = fmaf(q2.y, RL[5], s); s = fmaf(q3.x, RL[6], s);
    s = fmaf(q3.y, RL[7], s);
    return s;
}

// loop-top barrier: DMA + stores drained, then sync
__device__ __forceinline__ void tbar() {
    asm volatile("s_waitcnt vmcnt(0) lgkmcnt(0)" ::: "memory");
    __builtin_amdgcn_s_barrier();
    asm volatile("" ::: "memory");
}
// phase barrier: LDS writes visible, vmcnt NOT drained (DMA stays in flight)
__device__ __forceinline__ void pbar() {
    asm volatile("s_waitcnt lgkmcnt(0)" ::: "memory");
    __builtin_amdgcn_s_barrier();
    asm volatile("" ::: "memory");
}

typedef __attribute__((address_space(1))) const void gvoid_t;
typedef __attribute__((address_space(3))) void lvoid_t;

__global__ void __launch_bounds__(kThreads, 8)
wavelet_pipe(const float* __restrict__ x, float* __restrict__ out, int rows) {
    __shared__ __align__(16) float sx [SXF];
    __shared__ __align__(16) float sa1[SA1 + 2];
    __shared__ __align__(16) float sa2[SA2 + 2];
    __shared__ __align__(16) float sa3[SA3 + 2];

    const int tid = threadIdx.x;
    const int row = blockIdx.x;
    const float* __restrict__ xg = x + (size_t)row * kL0;

    // ---- staging of tile tt into sx (R7-verified DMA / R5-verified edge) ----
    auto stage = [&](int tt) {
        const int XB = (tt << 11) - 44;
        if (tt != 0 && tt != 7) {
            if (tid < 2) sx[2 + tid] = xg[XB + 2 + tid];
            const int wv = tid >> 6, lane = tid & 63;
            for (int c = wv; c <= 8; c += 4) {
                const int fo = 4 + (c << 8) + (lane << 2);   // 16B-aligned
                if (c < 8 || lane < 22)                       // cover [4, 2140)
                    __builtin_amdgcn_global_load_lds((gvoid_t*)(xg + XB + fo),
                                                     (lvoid_t*)(&sx[fo]), 16, 0, 0);
            }
        } else {
            const int t0  = (tt == 0) ? 44 : 4;
            const int thi = (tt == 0) ? 2140 : 2092;
            const int Nv  = (thi - t0) >> 2;
            for (int v = tid; v < Nv; v += kThreads) {
                const float4 val = *reinterpret_cast<const float4*>(xg + XB + t0 + 4 * v);
                sx[t0 + 4 * v]     = val.x; sx[t0 + 4 * v + 1] = val.y;
                sx[t0 + 4 * v + 2] = val.z; sx[t0 + 4 * v + 3] = val.w;
            }
            for (int t = 2 + tid; t < 2140; t += kThreads)
                if (t < t0 || t >= thi)
                    sx[t] = xg[reflect(XB + t, kL0)];
        }
    };

    stage(0);   // prologue

    for (int t = 0; t < 8; ++t) {
        const int O  = t << 11;
        const int A0 = (O >> 1) - 18;
        const int B0 = (O >> 2) - 6;

        tbar();   // sx(t) ready (drains DMA/loads/stores), buffer handoff

        // ---- a1: sa1[m] = a1ext[A0+m], window sx[2*mh+2 ..] ----
        for (int m = tid; m < SA1; m += kThreads) {
            const int g  = A0 + m;
            const int mh = (g >= 0 && g < kN1) ? m : (reflect(g, kN1) - A0);
            sa1[m] = tap8f2(&sx[2 * mh + 2]);
        }
        pbar();   // sx free from here on

        if (t < 7) stage(t + 1);   // DMA in flight across a2/a3/final

        // ---- a2: sa2[m] = a2ext[B0+m], window sa1[2*j ..] ----
        for (int m = tid; m < SA2; m += kThreads) {
            const int g = B0 + m;
            const int j = (g >= 0 && g < kN2) ? m : (reflect(g, kN2) - B0);
            sa2[m] = tap8f2(&sa1[2 * j]);
        }
        pbar();

        // ---- a3: sa3[m] = a3[O/8 + m], window sa2[2m ..] ----
        for (int m = tid; m < SA3; m += kThreads)
            sa3[m] = tap8f2(&sa2[2 * m]);
        pbar();

        // ---- final: low = W * a3; high = x - low (champion layout) ----
        {
            const float4* xr4 = reinterpret_cast<const float4*>(xg + O + 8 * tid);
            const float4 xv0 = xr4[0], xv1 = xr4[1];
            float a[7];
            #pragma unroll
            for (int m = 0; m < 7; ++m) a[m] = sa3[tid + m];
            float lo[8];
            #pragma unroll
            for (int r = 0; r < 8; ++r) {
                float s = a[0] * W.w[r][0];
                #pragma unroll
                for (int m = 1; m < 7; ++m) s = fmaf(a[m], W.w[r][m], s);
                lo[r] = s;
            }
            float* __restrict__ lowp  = out + (size_t)row * kL0 + O + 8 * tid;
            float* __restrict__ highp = lowp + (size_t)rows * kL0;
            reinterpret_cast<float4*>(lowp)[0]  = make_float4(lo[0], lo[1], lo[2], lo[3]);
            reinterpret_cast<float4*>(lowp)[1]  = make_float4(lo[4], lo[5], lo[6], lo[7]);
            reinterpret_cast<float4*>(highp)[0] = make_float4(xv0.x - lo[0], xv0.y - lo[1],
                                                              xv0.z - lo[2], xv0.w - lo[3]);
            reinterpret_cast<float4*>(highp)[1] = make_float4(xv1.x - lo[4], xv1.y - lo[5],
                                                              xv1.z - lo[6], xv1.w - lo[7]);
        }
        // loop-top tbar of t+1 handles end-of-tile sync
    }
}

extern "C" void kernel_launch(void* const* d_in, const int* in_sizes, int n_in,
                              void* d_out, int out_size, void* d_ws, size_t ws_size,
                              hipStream_t stream) {
    (void)n_in; (void)d_ws; (void)ws_size; (void)out_size;
    const float* x = (const float*)d_in[0];
    float* out = (float*)d_out;
    const int rows = in_sizes[0] / kL0;           // 2048
    hipLaunchKernelGGL(wavelet_pipe, dim3(rows), dim3(kThreads), 0, stream,
                       x, out, rows);
}